// Round 9
// baseline (417.621 us; speedup 1.0000x reference)
//
#include <hip/hip_runtime.h>

#define BB     256
#define TT     2048
#define DIN    10
#define UU     64
#define DOUT   2
#define CHUNK  64
#define NCHUNK (TT / CHUNK)
#define HISTP  67   // odd stride -> conflict-free column reads

typedef float f32x2 __attribute__((ext_vector_type(2)));
typedef float f32x4 __attribute__((ext_vector_type(4)));

// 2*log2(e): recurrence tracked as u = 1/(exp2(C*z)+1), h = 1-2u = tanh(z)
#define CSCALE 2.8853900817779268f

#if __has_builtin(__builtin_elementwise_fma)
__device__ __forceinline__ f32x2 pkfma(f32x2 a, f32x2 b, f32x2 c) {
    return __builtin_elementwise_fma(a, b, c);
}
#else
__device__ __forceinline__ f32x2 pkfma(f32x2 a, f32x2 b, f32x2 c) {
    f32x2 r; r.x = fmaf(a.x, b.x, c.x); r.y = fmaf(a.y, b.y, c.y); return r;
}
#endif

#if __has_builtin(__builtin_amdgcn_permlane32_swap) && __has_builtin(__builtin_amdgcn_permlane16_swap)
#define HAS_PL 1
#else
#define HAS_PL 0
#endif

template <int N> struct IC { static constexpr int value = N; };

#if HAS_PL
// Treated as BLACK BOXES: exact lane semantics are identified at runtime by
// the init-time probe; the weight-column mapping adapts to whatever they do.
__device__ __forceinline__ float swapadd32(float a, float b) {
    auto t = __builtin_amdgcn_permlane32_swap(__float_as_uint(a), __float_as_uint(b), false, false);
    return __uint_as_float(t[0]) + __uint_as_float(t[1]);
}
__device__ __forceinline__ float swapadd16(float a, float b) {
    auto t = __builtin_amdgcn_permlane16_swap(__float_as_uint(a), __float_as_uint(b), false, false);
    return __uint_as_float(t[0]) + __uint_as_float(t[1]);
}
#endif

__device__ __forceinline__ float swz_xor16(float v) {
    return __int_as_float(__builtin_amdgcn_ds_swizzle(__float_as_int(v), 0x401F));
}

// 15 DPP row-rotations writing directly into packed pk_fma operand pairs:
// hp[J/2].{x,y} = u from lane (l & 0x30) | ((r + J*dstep) & 15)
template <int J>
__device__ __forceinline__ void ror_fill(int hb, f32x2* hp) {
    float v = __int_as_float(__builtin_amdgcn_mov_dpp(hb, 0x120 + J, 0xF, 0xF, false));
    if constexpr ((J & 1) == 0) hp[J / 2].x = v; else hp[J / 2].y = v;
    if constexpr (J < 15) ror_fill<J + 1>(hb, hp);
}

// Reduce-scatter across the 4 k-quarters.
// MODE 0: 3 VALU permlane-swaps; column mapping derived by the init probe.
// MODE 2: shfl_xor + ds_swizzle fallback (proven R3-R8), columns r+16j.
template <int MODE>
__device__ __forceinline__ float reduce4(float p0, float p1, float p2, float p3, int l) {
#if HAS_PL
    if constexpr (MODE == 0) {
        float u02 = swapadd32(p0, p2);
        float u13 = swapadd32(p1, p3);
        return swapadd16(u02, u13);
    }
#endif
    {
        bool hi = (l & 32) != 0, od = (l & 16) != 0;
        float s0 = hi ? p0 : p2, s1 = hi ? p1 : p3;
        float r0 = __shfl_xor(s0, 32), r1 = __shfl_xor(s1, 32);
        float a0 = (hi ? p2 : p0) + r0;
        float a1 = (hi ? p3 : p1) + r1;
        float s2 = od ? a0 : a1;
        float r2 = swz_xor16(s2);
        return (od ? a1 : a0) + r2;
    }
}

__global__ __launch_bounds__(128) void rnn_scan_kernel(
    const float* __restrict__ x,    // [B,T,DIN]
    const float* __restrict__ Wx,   // [DIN,U]
    const float* __restrict__ Wh,   // [U,U]
    const float* __restrict__ bias, // [U]
    const float* __restrict__ Wd,   // [U,DOUT]
    const float* __restrict__ bd,   // [DOUT]
    float* __restrict__ out)        // [B,T,DOUT]
{
    // Wave 0 (consumer): pure recurrence. Wave 1 (producer): x-projection for
    // chunk c+1 and Dense epilogue for chunk c-1.
    __shared__ float xps[2][CHUNK * UU];
    __shared__ float hist[2][CHUNK * HISTP];
    __shared__ __align__(16) float xs[CHUNK * 12];
    __shared__ __align__(8)  f32x2 wdl2[UU];
    __shared__ int invt[4 * UU];               // probe scatter table (wave 0 only)

    const int tid = threadIdx.x;
    const int wid = tid >> 6;    // 0 = scan wave, 1 = producer wave
    const int l   = tid & 63;
    const int b   = blockIdx.x;
    const int g   = l >> 4;
    const int r   = l & 15;

    // --- probe DPP row_ror direction (init-only, direction-proof) ---
    int dstep;
    {
        int q = __builtin_amdgcn_mov_dpp(r, 0x121, 0xF, 0xF, false);
        dstep = (q - r) & 15;
    }

    // --- black-box identification of the permlane reduce network ------------
    int mode = 2;
    int cjmap[4] = { r, r + 16, r + 32, r + 48 };  // mode-2 layout
#if HAS_PL
    if (wid == 0) {
        bool ok = true;
        int lk[4];
        // 1) lambda-probe: slot k's single source lane for this output lane
#pragma unroll
        for (int k = 0; k < 4; ++k) {
            float p[4] = {0.f, 0.f, 0.f, 0.f};
            p[k] = 256.0f + (float)l;
            float z = swapadd16(swapadd32(p[0], p[2]), swapadd32(p[1], p[3]));
            ok = ok && (z >= 256.0f) && (z <= 319.0f) && (z == floorf(z));
            int v = (int)(z - 256.0f);
            lk[k] = v < 0 ? 0 : (v > 63 ? 63 : v);
        }
        // 2) the 4 sources must span all 4 k-quarters
        int qm = (1 << (lk[0] >> 4)) | (1 << (lk[1] >> 4)) |
                 (1 << (lk[2] >> 4)) | (1 << (lk[3] >> 4));
        ok = ok && (qm == 0xF);
        // 3) per-slot inverse permutation via LDS scatter (collision -> -1 stays)
#pragma unroll
        for (int k = 0; k < 4; ++k) invt[k * UU + l] = -1;
#pragma unroll
        for (int k = 0; k < 4; ++k) invt[k * UU + lk[k]] = l;
        int cjp[4];
#pragma unroll
        for (int k = 0; k < 4; ++k) {
            int c = invt[k * UU + l];
            ok = ok && (c >= 0);
            cjp[k] = c < 0 ? 0 : (c > 63 ? 63 : c);
        }
        // 4) two exact end-to-end synthetic verifications (integer fp32)
        bool pass = ok;
#pragma unroll
        for (int t = 0; t < 2; ++t) {
            const int mu = t ? 3 : 5, au = t ? 1 : 3;
            const int mw = t ? 7 : 3, nw = t ? 11 : 5, aw = t ? 2 : 0;
            float utst = (float)(((mu * l + au) & 7) - 3);
            f32x2 hp[8];
            hp[0].x = utst;
            ror_fill<1>(__float_as_int(utst), hp);
            float p[4];
#pragma unroll
            for (int j = 0; j < 4; ++j) {
                float a = 0.f;
#pragma unroll
                for (int m = 0; m < 8; ++m) {
                    int k0 = 16 * g + ((r + (2 * m) * dstep) & 15);
                    int k1 = 16 * g + ((r + (2 * m + 1) * dstep) & 15);
                    float w0 = (float)(((mw * k0 + nw * cjp[j] + aw) & 7) - 3);
                    float w1 = (float)(((mw * k1 + nw * cjp[j] + aw) & 7) - 3);
                    a = fmaf(hp[m].x, w0, a);
                    a = fmaf(hp[m].y, w1, a);
                }
                p[j] = a;
            }
            float z = swapadd16(swapadd32(p[0], p[2]), swapadd32(p[1], p[3]));
            float ref = 0.f;
            for (int k = 0; k < UU; ++k) {
                float uk = (float)(((mu * k + au) & 7) - 3);
                float wk = (float)(((mw * k + nw * l + aw) & 7) - 3);
                ref = fmaf(uk, wk, ref);
            }
            pass = pass && (z == ref);
        }
        if (__all(pass ? 1 : 0)) {
            mode = 0;
#pragma unroll
            for (int k = 0; k < 4; ++k) cjmap[k] = cjp[k];
        }
    }
#endif

    // --- Wh fragments, scaled: W2'[k,c] = -2*C*Wh[k,c]; columns from cjmap ---
    f32x2 w2[4][8];
#pragma unroll
    for (int j = 0; j < 4; ++j) {
        const int cj = cjmap[j];
#pragma unroll
        for (int m = 0; m < 8; ++m) {
            const int k0 = 16 * g + ((r + (2 * m) * dstep) & 15);
            const int k1 = 16 * g + ((r + (2 * m + 1) * dstep) & 15);
            f32x2 w;
            w.x = -2.0f * CSCALE * Wh[(size_t)k0 * UU + cj];
            w.y = -2.0f * CSCALE * Wh[(size_t)k1 * UU + cj];
            w2[j][m] = w;
        }
    }

    // --- producer-wave constants ---
    f32x2 wxp[5];
#pragma unroll
    for (int d2 = 0; d2 < 5; ++d2) {
        f32x2 w;
        w.x = CSCALE * Wx[(2 * d2) * UU + l];
        w.y = CSCALE * Wx[(2 * d2 + 1) * UU + l];
        wxp[d2] = w;
    }
    float Kl;
    {
        float s = bias[l];
        for (int k = 0; k < UU; ++k) s += Wh[(size_t)k * UU + l];
        Kl = CSCALE * s;
    }
    f32x2 bdd;
    {
        float s0 = bd[0], s1 = bd[1];
        for (int k = 0; k < UU; ++k) { s0 += Wd[k * DOUT + 0]; s1 += Wd[k * DOUT + 1]; }
        bdd.x = s0; bdd.y = s1;
    }
    if (wid == 0) {
        f32x2 w; w.x = -2.0f * Wd[l * DOUT + 0]; w.y = -2.0f * Wd[l * DOUT + 1];
        wdl2[l] = w;
    }

    const float* xb = x + (size_t)b * TT * DIN;
    float*       ob = out + (size_t)b * TT * DOUT;

    // --- producer helpers ---
    auto fill_xps = [&](int cn) {
        const f32x2* xr = (const f32x2*)(xb + (size_t)(cn * CHUNK + l) * DIN);
        f32x2 v0 = xr[0], v1 = xr[1], v2 = xr[2], v3 = xr[3], v4 = xr[4];
        f32x2* dst = (f32x2*)&xs[l * 12];
        dst[0] = v0; dst[1] = v1; dst[2] = v2; dst[3] = v3; dst[4] = v4;
        float* xp_out = &xps[cn & 1][l];
#pragma unroll 4
        for (int s = 0; s < CHUNK; ++s) {
            const float* p = &xs[s * 12];
            f32x4 xa = ((const f32x4*)p)[0];
            f32x4 xc = ((const f32x4*)p)[1];
            f32x2 xe = ((const f32x2*)p)[4];
            f32x2 acc = {Kl, 0.0f};
            acc = pkfma(__builtin_shufflevector(xa, xa, 0, 1), wxp[0], acc);
            acc = pkfma(__builtin_shufflevector(xa, xa, 2, 3), wxp[1], acc);
            acc = pkfma(__builtin_shufflevector(xc, xc, 0, 1), wxp[2], acc);
            acc = pkfma(__builtin_shufflevector(xc, xc, 2, 3), wxp[3], acc);
            acc = pkfma(xe, wxp[4], acc);
            xp_out[s * UU] = acc.x + acc.y;
        }
    };
    auto dense_chunk = [&](int cd) {
        const float* hrow = &hist[cd & 1][l * HISTP];
        f32x2 acc = bdd;
#pragma unroll 8
        for (int k = 0; k < UU; ++k) {
            float u = hrow[k];
            f32x2 uu; uu.x = u; uu.y = u;
            acc = pkfma(uu, wdl2[k], acc);
        }
        float2 o; o.x = acc.x; o.y = acc.y;
        *(float2*)(ob + (size_t)(cd * CHUNK + l) * DOUT) = o;
    };

    // prologue: producer fills chunk 0's x-projection
    if (wid == 1) fill_xps(0);
    __syncthreads();

    auto scan_chunk = [&](auto MC, int c, float u) {
        constexpr int MODE = decltype(MC)::value;
        const float* xpsrc = &xps[c & 1][l];
        float* hdst = &hist[c & 1][l];
        float xcur = xpsrc[0];
#pragma unroll 8
        for (int s = 0; s < CHUNK; ++s) {
            // 1-deep prefetch: next step's xp issues a full step before use
            float xnext = xpsrc[((s + 1) & (CHUNK - 1)) * UU];
            // broadcast u within each 16-lane row, direct to pk pairs
            f32x2 hp[8];
            hp[0].x = u;
            ror_fill<1>(__float_as_int(u), hp);
            // dot with -2C*Wh (4 accumulators, R6 structure)
            f32x2 a0 = {0.f,0.f}, a1 = {0.f,0.f}, a2 = {0.f,0.f}, a3 = {0.f,0.f};
#pragma unroll
            for (int m = 0; m < 8; ++m) {
                a0 = pkfma(hp[m], w2[0][m], a0);
                a1 = pkfma(hp[m], w2[1][m], a1);
                a2 = pkfma(hp[m], w2[2][m], a2);
                a3 = pkfma(hp[m], w2[3][m], a3);
            }
            float zr = reduce4<MODE>(a0.x + a0.y, a1.x + a1.y,
                                     a2.x + a2.y, a3.x + a3.y, l);
            float zp = zr + xcur;               // = C*z
#if __has_builtin(__builtin_amdgcn_exp2f)
            float e = __builtin_amdgcn_exp2f(zp);
#else
            float e = exp2f(zp);
#endif
            u = __builtin_amdgcn_rcpf(e + 1.0f);  // u = 1/(e^{2z}+1); h = 1-2u
            hdst[s * HISTP] = u;
            xcur = xnext;
        }
        return u;
    };

    float u = 0.5f;  // h_0 = 0
    for (int c = 0; c < NCHUNK; ++c) {
        if (wid == 0) {
            if (mode == 0) u = scan_chunk(IC<0>{}, c, u);
            else           u = scan_chunk(IC<2>{}, c, u);
        } else {
            if (c + 1 < NCHUNK) fill_xps(c + 1);
            if (c > 0)          dense_chunk(c - 1);
        }
        __syncthreads();
    }
    if (wid == 1) dense_chunk(NCHUNK - 1);
}

extern "C" void kernel_launch(void* const* d_in, const int* in_sizes, int n_in,
                              void* d_out, int out_size, void* d_ws, size_t ws_size,
                              hipStream_t stream) {
    const float* x    = (const float*)d_in[0];
    const float* Wx   = (const float*)d_in[1];
    const float* Wh   = (const float*)d_in[2];
    const float* bias = (const float*)d_in[3];
    const float* Wd   = (const float*)d_in[4];
    const float* bd   = (const float*)d_in[5];
    float* out = (float*)d_out;

    rnn_scan_kernel<<<BB, 128, 0, stream>>>(x, Wx, Wh, bias, Wd, bd, out);
}

// Round 10
// 384.403 us; speedup vs baseline: 1.0864x; 1.0864x over previous
//
#include <hip/hip_runtime.h>

#define BB     256
#define TT     2048
#define DIN    10
#define UU     64
#define DOUT   2
#define CHUNK  64
#define NCHUNK (TT / CHUNK)
#define HISTP  67   // odd stride -> conflict-free column reads

typedef float f32x2 __attribute__((ext_vector_type(2)));
typedef float f32x4 __attribute__((ext_vector_type(4)));

// 2*log2(e): recurrence tracked as u = 1/(exp2(C*z)+1), h = 1-2u = tanh(z)
#define CSCALE 2.8853900817779268f

#if __has_builtin(__builtin_elementwise_fma)
__device__ __forceinline__ f32x2 pkfma(f32x2 a, f32x2 b, f32x2 c) {
    return __builtin_elementwise_fma(a, b, c);
}
#else
__device__ __forceinline__ f32x2 pkfma(f32x2 a, f32x2 b, f32x2 c) {
    f32x2 r; r.x = fmaf(a.x, b.x, c.x); r.y = fmaf(a.y, b.y, c.y); return r;
}
#endif

#if __has_builtin(__builtin_amdgcn_permlane32_swap) && __has_builtin(__builtin_amdgcn_permlane16_swap)
#define HAS_PL 1
#else
#define HAS_PL 0
#endif

template <int N> struct IC { static constexpr int value = N; };

#if HAS_PL
// Sum of both outputs -> invariant to output-order convention. The remaining
// operand-role ambiguity is resolved by the init-time lambda-probe (cjmap).
__device__ __forceinline__ float swapadd32(float a, float b) {
    auto t = __builtin_amdgcn_permlane32_swap(__float_as_uint(a), __float_as_uint(b), false, false);
    return __uint_as_float(t[0]) + __uint_as_float(t[1]);
}
__device__ __forceinline__ float swapadd16(float a, float b) {
    auto t = __builtin_amdgcn_permlane16_swap(__float_as_uint(a), __float_as_uint(b), false, false);
    return __uint_as_float(t[0]) + __uint_as_float(t[1]);
}
#endif

__device__ __forceinline__ float swz_xor16(float v) {
    return __int_as_float(__builtin_amdgcn_ds_swizzle(__float_as_int(v), 0x401F));
}

// 15 DPP row-rotations writing directly into packed pk_fma operand pairs:
// hp[J/2].{x,y} = u from lane (l & 0x30) | ((r + J*dstep) & 15)
template <int J>
__device__ __forceinline__ void ror_fill(int hb, f32x2* hp) {
    float v = __int_as_float(__builtin_amdgcn_mov_dpp(hb, 0x120 + J, 0xF, 0xF, false));
    if constexpr ((J & 1) == 0) hp[J / 2].x = v; else hp[J / 2].y = v;
    if constexpr (J < 15) ror_fill<J + 1>(hb, hp);
}

// Reduce-scatter across the 4 k-quarters.
// MODE 0: 3 VALU permlane-swaps; weight columns from the init lambda-probe.
// MODE 2: shfl_xor + ds_swizzle fallback (proven R3-R8), columns r+16j.
template <int MODE>
__device__ __forceinline__ float reduce4(float p0, float p1, float p2, float p3, int l) {
#if HAS_PL
    if constexpr (MODE == 0) {
        float u02 = swapadd32(p0, p2);
        float u13 = swapadd32(p1, p3);
        return swapadd16(u02, u13);
    }
#endif
    {
        bool hi = (l & 32) != 0, od = (l & 16) != 0;
        float s0 = hi ? p0 : p2, s1 = hi ? p1 : p3;
        float r0 = __shfl_xor(s0, 32), r1 = __shfl_xor(s1, 32);
        float a0 = (hi ? p2 : p0) + r0;
        float a1 = (hi ? p3 : p1) + r1;
        float s2 = od ? a0 : a1;
        float r2 = swz_xor16(s2);
        return (od ? a1 : a0) + r2;
    }
}

__global__ __launch_bounds__(128) void rnn_scan_kernel(
    const float* __restrict__ x,    // [B,T,DIN]
    const float* __restrict__ Wx,   // [DIN,U]
    const float* __restrict__ Wh,   // [U,U]
    const float* __restrict__ bias, // [U]
    const float* __restrict__ Wd,   // [U,DOUT]
    const float* __restrict__ bd,   // [DOUT]
    float* __restrict__ out)        // [B,T,DOUT]
{
    // Wave 0 (consumer): pure recurrence. Wave 1 (producer): x-projection for
    // chunk c+1 and Dense epilogue for chunk c-1.  (Exact R6 structure.)
    __shared__ float xps[2][CHUNK * UU];
    __shared__ float hist[2][CHUNK * HISTP];
    __shared__ __align__(16) float xs[CHUNK * 12];
    __shared__ __align__(8)  f32x2 wdl2[UU];
    __shared__ int invt[4 * UU];               // lambda-probe scatter (wave 0)

    const int tid = threadIdx.x;
    const int wid = tid >> 6;    // 0 = scan wave, 1 = producer wave
    const int l   = tid & 63;
    const int b   = blockIdx.x;
    const int g   = l >> 4;
    const int r   = l & 15;

    // --- probe DPP row_ror direction (init-only, direction-proof) ---
    int dstep;
    {
        int q = __builtin_amdgcn_mov_dpp(r, 0x121, 0xF, 0xF, false);
        dstep = (q - r) & 15;
    }

    // --- lambda-probe: identify the permlane reduce network (any convention) --
    int mode = 2;
    int cjmap[4] = { r, r + 16, r + 32, r + 48 };  // mode-2 layout
#if HAS_PL
    if (wid == 0) {
        bool ok = true;
        int lk[4];
        // slot k's single source lane for this output lane (exact integer fp32)
#pragma unroll
        for (int k = 0; k < 4; ++k) {
            float p[4] = {0.f, 0.f, 0.f, 0.f};
            p[k] = 256.0f + (float)l;
            float z = swapadd16(swapadd32(p[0], p[2]), swapadd32(p[1], p[3]));
            ok = ok && (z >= 256.0f) && (z <= 319.0f);
            int v = (int)z - 256;
            lk[k] = v < 0 ? 0 : (v > 63 ? 63 : v);
        }
        // sources must span all 4 k-quarters (proves full 64-k coverage)
        int qm = (1 << (lk[0] >> 4)) | (1 << (lk[1] >> 4)) |
                 (1 << (lk[2] >> 4)) | (1 << (lk[3] >> 4));
        ok = ok && (qm == 0xF);
        // per-slot inverse permutation via LDS scatter (collision -> -1 stays)
#pragma unroll
        for (int k = 0; k < 4; ++k) invt[k * UU + l] = -1;
#pragma unroll
        for (int k = 0; k < 4; ++k) invt[k * UU + lk[k]] = l;
#pragma unroll
        for (int k = 0; k < 4; ++k) {
            int c = invt[k * UU + l];
            ok = ok && (c >= 0);
            cjmap[k] = (c < 0) ? cjmap[k] : (c > 63 ? 63 : c);
        }
        if (__all(ok ? 1 : 0)) mode = 0;
        else { cjmap[0] = r; cjmap[1] = r + 16; cjmap[2] = r + 32; cjmap[3] = r + 48; }
    }
#endif

    // --- Wh fragments, scaled: W2'[k,c] = -2*C*Wh[k,c]; columns from cjmap ---
    f32x2 w2[4][8];
#pragma unroll
    for (int j = 0; j < 4; ++j) {
        const int cj = cjmap[j];
#pragma unroll
        for (int m = 0; m < 8; ++m) {
            const int k0 = 16 * g + ((r + (2 * m) * dstep) & 15);
            const int k1 = 16 * g + ((r + (2 * m + 1) * dstep) & 15);
            f32x2 w;
            w.x = -2.0f * CSCALE * Wh[(size_t)k0 * UU + cj];
            w.y = -2.0f * CSCALE * Wh[(size_t)k1 * UU + cj];
            w2[j][m] = w;
        }
    }

    // --- producer-wave constants ---
    f32x2 wxp[5];
#pragma unroll
    for (int d2 = 0; d2 < 5; ++d2) {
        f32x2 w;
        w.x = CSCALE * Wx[(2 * d2) * UU + l];
        w.y = CSCALE * Wx[(2 * d2 + 1) * UU + l];
        wxp[d2] = w;
    }
    float Kl;
    {
        float s = bias[l];
        for (int k = 0; k < UU; ++k) s += Wh[(size_t)k * UU + l];
        Kl = CSCALE * s;
    }
    f32x2 bdd;
    {
        float s0 = bd[0], s1 = bd[1];
        for (int k = 0; k < UU; ++k) { s0 += Wd[k * DOUT + 0]; s1 += Wd[k * DOUT + 1]; }
        bdd.x = s0; bdd.y = s1;
    }
    if (wid == 0) {
        f32x2 w; w.x = -2.0f * Wd[l * DOUT + 0]; w.y = -2.0f * Wd[l * DOUT + 1];
        wdl2[l] = w;
    }

    const float* xb = x + (size_t)b * TT * DIN;
    float*       ob = out + (size_t)b * TT * DOUT;

    // --- producer helpers ---
    auto fill_xps = [&](int cn) {
        const f32x2* xr = (const f32x2*)(xb + (size_t)(cn * CHUNK + l) * DIN);
        f32x2 v0 = xr[0], v1 = xr[1], v2 = xr[2], v3 = xr[3], v4 = xr[4];
        f32x2* dst = (f32x2*)&xs[l * 12];
        dst[0] = v0; dst[1] = v1; dst[2] = v2; dst[3] = v3; dst[4] = v4;
        float* xp_out = &xps[cn & 1][l];
#pragma unroll 4
        for (int s = 0; s < CHUNK; ++s) {
            const float* p = &xs[s * 12];
            f32x4 xa = ((const f32x4*)p)[0];
            f32x4 xc = ((const f32x4*)p)[1];
            f32x2 xe = ((const f32x2*)p)[4];
            f32x2 acc = {Kl, 0.0f};
            acc = pkfma(__builtin_shufflevector(xa, xa, 0, 1), wxp[0], acc);
            acc = pkfma(__builtin_shufflevector(xa, xa, 2, 3), wxp[1], acc);
            acc = pkfma(__builtin_shufflevector(xc, xc, 0, 1), wxp[2], acc);
            acc = pkfma(__builtin_shufflevector(xc, xc, 2, 3), wxp[3], acc);
            acc = pkfma(xe, wxp[4], acc);
            xp_out[s * UU] = acc.x + acc.y;
        }
    };
    auto dense_chunk = [&](int cd) {
        const float* hrow = &hist[cd & 1][l * HISTP];
        f32x2 acc = bdd;
#pragma unroll 8
        for (int k = 0; k < UU; ++k) {
            float u = hrow[k];
            f32x2 uu; uu.x = u; uu.y = u;
            acc = pkfma(uu, wdl2[k], acc);
        }
        float2 o; o.x = acc.x; o.y = acc.y;
        *(float2*)(ob + (size_t)(cd * CHUNK + l) * DOUT) = o;
    };

    // prologue: producer fills chunk 0's x-projection
    if (wid == 1) fill_xps(0);
    __syncthreads();

    // --- scan: EXACT R6 body (no manual prefetch rotation) ---
    auto scan_chunk = [&](auto MC, int c, float u) {
        constexpr int MODE = decltype(MC)::value;
        const float* xpsrc = &xps[c & 1][l];
        float* hdst = &hist[c & 1][l];
#pragma unroll 8
        for (int s = 0; s < CHUNK; ++s) {
            float xpv = xpsrc[s * UU];          // independent of u -> hoistable
            // broadcast u within each 16-lane row, direct to pk pairs
            f32x2 hp[8];
            hp[0].x = u;
            ror_fill<1>(__float_as_int(u), hp);
            // dot with -2C*Wh (4 accumulators)
            f32x2 a0 = {0.f,0.f}, a1 = {0.f,0.f}, a2 = {0.f,0.f}, a3 = {0.f,0.f};
#pragma unroll
            for (int m = 0; m < 8; ++m) {
                a0 = pkfma(hp[m], w2[0][m], a0);
                a1 = pkfma(hp[m], w2[1][m], a1);
                a2 = pkfma(hp[m], w2[2][m], a2);
                a3 = pkfma(hp[m], w2[3][m], a3);
            }
            float zr = reduce4<MODE>(a0.x + a0.y, a1.x + a1.y,
                                     a2.x + a2.y, a3.x + a3.y, l);
            float zp = zr + xpv;                // = C*z
#if __has_builtin(__builtin_amdgcn_exp2f)
            float e = __builtin_amdgcn_exp2f(zp);
#else
            float e = exp2f(zp);
#endif
            u = __builtin_amdgcn_rcpf(e + 1.0f);  // u = 1/(e^{2z}+1); h = 1-2u
            hdst[s * HISTP] = u;
        }
        return u;
    };

    float u = 0.5f;  // h_0 = 0
    for (int c = 0; c < NCHUNK; ++c) {
        if (wid == 0) {
            if (mode == 0) u = scan_chunk(IC<0>{}, c, u);
            else           u = scan_chunk(IC<2>{}, c, u);
        } else {
            if (c + 1 < NCHUNK) fill_xps(c + 1);
            if (c > 0)          dense_chunk(c - 1);
        }
        __syncthreads();
    }
    if (wid == 1) dense_chunk(NCHUNK - 1);
}

extern "C" void kernel_launch(void* const* d_in, const int* in_sizes, int n_in,
                              void* d_out, int out_size, void* d_ws, size_t ws_size,
                              hipStream_t stream) {
    const float* x    = (const float*)d_in[0];
    const float* Wx   = (const float*)d_in[1];
    const float* Wh   = (const float*)d_in[2];
    const float* bias = (const float*)d_in[3];
    const float* Wd   = (const float*)d_in[4];
    const float* bd   = (const float*)d_in[5];
    float* out = (float*)d_out;

    rnn_scan_kernel<<<BB, 128, 0, stream>>>(x, Wx, Wh, bias, Wd, bd, out);
}

// Round 11
// 347.045 us; speedup vs baseline: 1.2034x; 1.1076x over previous
//
#include <hip/hip_runtime.h>

#define BB     256
#define TT     2048
#define DIN    10
#define UU     64
#define DOUT   2
#define CHUNK  64
#define NCHUNK (TT / CHUNK)
#define HISTP  67   // odd stride -> conflict-free column reads

typedef float f32x2 __attribute__((ext_vector_type(2)));
typedef float f32x4 __attribute__((ext_vector_type(4)));

// 2*log2(e): recurrence tracked as u = 1/(exp2(C*z)+1), h = 1-2u = tanh(z)
#define CSCALE 2.8853900817779268f

#if __has_builtin(__builtin_elementwise_fma)
__device__ __forceinline__ f32x2 pkfma(f32x2 a, f32x2 b, f32x2 c) {
    return __builtin_elementwise_fma(a, b, c);
}
#else
__device__ __forceinline__ f32x2 pkfma(f32x2 a, f32x2 b, f32x2 c) {
    f32x2 r; r.x = fmaf(a.x, b.x, c.x); r.y = fmaf(a.y, b.y, c.y); return r;
}
#endif

__device__ __forceinline__ float swz_xor16(float v) {
    return __int_as_float(__builtin_amdgcn_ds_swizzle(__float_as_int(v), 0x401F));
}

// 15 DPP row-rotations writing directly into packed pk_fma operand pairs:
// hp[J/2].{x,y} = u from lane (l & 0x30) | ((r + J*dstep) & 15)
template <int J>
__device__ __forceinline__ void ror_fill(int hb, f32x2* hp) {
    float v = __int_as_float(__builtin_amdgcn_mov_dpp(hb, 0x120 + J, 0xF, 0xF, false));
    if constexpr ((J & 1) == 0) hp[J / 2].x = v; else hp[J / 2].y = v;
    if constexpr (J < 15) ror_fill<J + 1>(hb, hp);
}

// Parallel reduce-scatter: slot j of lane l holds unit (l ^ 16j)'s partial over
// k-quarter (l>>4). Lane l's full sum needs ONE value from each of l^16, l^32,
// l^48 — three INDEPENDENT DS fetches that pipeline (~140 cyc total instead of
// two serial round-trips ~240 cyc). Quarters {g, g^1, g^2, g^3} cover all 4.
__device__ __forceinline__ float reduce4(float q0, float q1, float q2, float q3) {
    float r1 = swz_xor16(q1);        // from l^16: its slot-1 = unit l, quarter g^1
    float r2 = __shfl_xor(q2, 32);   // from l^32: its slot-2 = unit l, quarter g^2
    float r3 = __shfl_xor(q3, 48);   // from l^48: its slot-3 = unit l, quarter g^3
    return (q0 + r1) + (r2 + r3);
}

__global__ __launch_bounds__(128) void rnn_scan_kernel(
    const float* __restrict__ x,    // [B,T,DIN]
    const float* __restrict__ Wx,   // [DIN,U]
    const float* __restrict__ Wh,   // [U,U]
    const float* __restrict__ bias, // [U]
    const float* __restrict__ Wd,   // [U,DOUT]
    const float* __restrict__ bd,   // [DOUT]
    float* __restrict__ out)        // [B,T,DOUT]
{
    // Wave 0 (consumer): pure recurrence. Wave 1 (producer): x-projection for
    // chunk c+1 and Dense epilogue for chunk c-1.  (Exact R6 structure.)
    __shared__ float xps[2][CHUNK * UU];       // scaled x-projection (+K) per chunk
    __shared__ float hist[2][CHUNK * HISTP];   // u history per chunk
    __shared__ __align__(16) float xs[CHUNK * 12];
    __shared__ __align__(8)  f32x2 wdl2[UU];   // -2*Wd rows

    const int tid = threadIdx.x;
    const int wid = tid >> 6;    // 0 = scan wave, 1 = producer wave
    const int l   = tid & 63;
    const int b   = blockIdx.x;
    const int g   = l >> 4;
    const int r   = l & 15;

    // --- probe DPP row_ror direction (init-only, direction-proof) ---
    int dstep;
    {
        int q = __builtin_amdgcn_mov_dpp(r, 0x121, 0xF, 0xF, false);
        dstep = (q - r) & 15;
    }

    // --- Wh fragments, scaled: W2'[k,c] = -2*C*Wh[k,c].
    //     Slot j covers unit (l ^ 16j) over k-quarter g (parallel-reduce layout).
    f32x2 w2[4][8];
#pragma unroll
    for (int j = 0; j < 4; ++j) {
        const int cj = l ^ (16 * j);
#pragma unroll
        for (int m = 0; m < 8; ++m) {
            const int k0 = 16 * g + ((r + (2 * m) * dstep) & 15);
            const int k1 = 16 * g + ((r + (2 * m + 1) * dstep) & 15);
            f32x2 w;
            w.x = -2.0f * CSCALE * Wh[(size_t)k0 * UU + cj];
            w.y = -2.0f * CSCALE * Wh[(size_t)k1 * UU + cj];
            w2[j][m] = w;
        }
    }

    // --- producer-wave constants ---
    f32x2 wxp[5];
#pragma unroll
    for (int d2 = 0; d2 < 5; ++d2) {
        f32x2 w;
        w.x = CSCALE * Wx[(2 * d2) * UU + l];
        w.y = CSCALE * Wx[(2 * d2 + 1) * UU + l];
        wxp[d2] = w;
    }
    float Kl;
    {
        float s = bias[l];
        for (int k = 0; k < UU; ++k) s += Wh[(size_t)k * UU + l];
        Kl = CSCALE * s;
    }
    f32x2 bdd;
    {
        float s0 = bd[0], s1 = bd[1];
        for (int k = 0; k < UU; ++k) { s0 += Wd[k * DOUT + 0]; s1 += Wd[k * DOUT + 1]; }
        bdd.x = s0; bdd.y = s1;
    }
    if (wid == 0) {
        f32x2 w; w.x = -2.0f * Wd[l * DOUT + 0]; w.y = -2.0f * Wd[l * DOUT + 1];
        wdl2[l] = w;
    }

    const float* xb = x + (size_t)b * TT * DIN;
    float*       ob = out + (size_t)b * TT * DOUT;

    // --- producer helpers ---
    auto fill_xps = [&](int cn) {
        const f32x2* xr = (const f32x2*)(xb + (size_t)(cn * CHUNK + l) * DIN);
        f32x2 v0 = xr[0], v1 = xr[1], v2 = xr[2], v3 = xr[3], v4 = xr[4];
        f32x2* dst = (f32x2*)&xs[l * 12];
        dst[0] = v0; dst[1] = v1; dst[2] = v2; dst[3] = v3; dst[4] = v4;
        float* xp_out = &xps[cn & 1][l];
#pragma unroll 4
        for (int s = 0; s < CHUNK; ++s) {
            const float* p = &xs[s * 12];
            f32x4 xa = ((const f32x4*)p)[0];
            f32x4 xc = ((const f32x4*)p)[1];
            f32x2 xe = ((const f32x2*)p)[4];
            f32x2 acc = {Kl, 0.0f};
            acc = pkfma(__builtin_shufflevector(xa, xa, 0, 1), wxp[0], acc);
            acc = pkfma(__builtin_shufflevector(xa, xa, 2, 3), wxp[1], acc);
            acc = pkfma(__builtin_shufflevector(xc, xc, 0, 1), wxp[2], acc);
            acc = pkfma(__builtin_shufflevector(xc, xc, 2, 3), wxp[3], acc);
            acc = pkfma(xe, wxp[4], acc);
            xp_out[s * UU] = acc.x + acc.y;
        }
    };
    auto dense_chunk = [&](int cd) {
        const float* hrow = &hist[cd & 1][l * HISTP];
        f32x2 acc = bdd;
#pragma unroll 8
        for (int k = 0; k < UU; ++k) {
            float u = hrow[k];
            f32x2 uu; uu.x = u; uu.y = u;
            acc = pkfma(uu, wdl2[k], acc);
        }
        float2 o; o.x = acc.x; o.y = acc.y;
        *(float2*)(ob + (size_t)(cd * CHUNK + l) * DOUT) = o;
    };

    // prologue: producer fills chunk 0's x-projection
    if (wid == 1) fill_xps(0);
    __syncthreads();

    // --- scan: EXACT R6 body; only reduce4 differs (parallel 3-fetch) ---
    auto scan_chunk = [&](int c, float u) {
        const float* xpsrc = &xps[c & 1][l];
        float* hdst = &hist[c & 1][l];
#pragma unroll 8
        for (int s = 0; s < CHUNK; ++s) {
            float xpv = xpsrc[s * UU];          // independent of u -> hoistable
            // broadcast u within each 16-lane row, direct to pk pairs
            f32x2 hp[8];
            hp[0].x = u;
            ror_fill<1>(__float_as_int(u), hp);
            // dot with -2C*Wh (4 accumulators)
            f32x2 a0 = {0.f,0.f}, a1 = {0.f,0.f}, a2 = {0.f,0.f}, a3 = {0.f,0.f};
#pragma unroll
            for (int m = 0; m < 8; ++m) {
                a0 = pkfma(hp[m], w2[0][m], a0);
                a1 = pkfma(hp[m], w2[1][m], a1);
                a2 = pkfma(hp[m], w2[2][m], a2);
                a3 = pkfma(hp[m], w2[3][m], a3);
            }
            float zr = reduce4(a0.x + a0.y, a1.x + a1.y,
                               a2.x + a2.y, a3.x + a3.y);
            float zp = zr + xpv;                // = C*z
#if __has_builtin(__builtin_amdgcn_exp2f)
            float e = __builtin_amdgcn_exp2f(zp);
#else
            float e = exp2f(zp);
#endif
            u = __builtin_amdgcn_rcpf(e + 1.0f);  // u = 1/(e^{2z}+1); h = 1-2u
            hdst[s * HISTP] = u;
        }
        return u;
    };

    float u = 0.5f;  // h_0 = 0
    for (int c = 0; c < NCHUNK; ++c) {
        if (wid == 0) {
            u = scan_chunk(c, u);
        } else {
            if (c + 1 < NCHUNK) fill_xps(c + 1);
            if (c > 0)          dense_chunk(c - 1);
        }
        __syncthreads();
    }
    if (wid == 1) dense_chunk(NCHUNK - 1);
}

extern "C" void kernel_launch(void* const* d_in, const int* in_sizes, int n_in,
                              void* d_out, int out_size, void* d_ws, size_t ws_size,
                              hipStream_t stream) {
    const float* x    = (const float*)d_in[0];
    const float* Wx   = (const float*)d_in[1];
    const float* Wh   = (const float*)d_in[2];
    const float* bias = (const float*)d_in[3];
    const float* Wd   = (const float*)d_in[4];
    const float* bd   = (const float*)d_in[5];
    float* out = (float*)d_out;

    rnn_scan_kernel<<<BB, 128, 0, stream>>>(x, Wx, Wh, bias, Wd, bd, out);
}

// Round 12
// 346.850 us; speedup vs baseline: 1.2040x; 1.0006x over previous
//
#include <hip/hip_runtime.h>

#define BB     256
#define TT     2048
#define DIN    10
#define UU     64
#define DOUT   2
#define CHUNK  64
#define NCHUNK (TT / CHUNK)
#define HISTP  67   // odd stride -> conflict-free column reads

typedef float f32x2 __attribute__((ext_vector_type(2)));
typedef float f32x4 __attribute__((ext_vector_type(4)));

// 2*log2(e): recurrence tracked as u = 1/(exp2(C*z)+1), h = 1-2u = tanh(z)
#define CSCALE 2.8853900817779268f

#if __has_builtin(__builtin_elementwise_fma)
__device__ __forceinline__ f32x2 pkfma(f32x2 a, f32x2 b, f32x2 c) {
    return __builtin_elementwise_fma(a, b, c);
}
#else
__device__ __forceinline__ f32x2 pkfma(f32x2 a, f32x2 b, f32x2 c) {
    f32x2 r; r.x = fmaf(a.x, b.x, c.x); r.y = fmaf(a.y, b.y, c.y); return r;
}
#endif

// 15 DPP row-rotations writing directly into packed pk_fma operand pairs:
// hp[J/2].{x,y} = u from lane (l & 0x30) | ((r + J*dstep) & 15)
template <int J>
__device__ __forceinline__ void ror_fill(int hb, f32x2* hp) {
    float v = __int_as_float(__builtin_amdgcn_mov_dpp(hb, 0x120 + J, 0xF, 0xF, false));
    if constexpr ((J & 1) == 0) hp[J / 2].x = v; else hp[J / 2].y = v;
    if constexpr (J < 15) ror_fill<J + 1>(hb, hp);
}

__global__ __launch_bounds__(128) void rnn_scan_kernel(
    const float* __restrict__ x,    // [B,T,DIN]
    const float* __restrict__ Wx,   // [DIN,U]
    const float* __restrict__ Wh,   // [U,U]
    const float* __restrict__ bias, // [U]
    const float* __restrict__ Wd,   // [U,DOUT]
    const float* __restrict__ bd,   // [DOUT]
    float* __restrict__ out)        // [B,T,DOUT]
{
    // Wave 0 (consumer): pure recurrence. Wave 1 (producer): x-projection for
    // chunk c+1 and Dense epilogue for chunk c-1.  (Exact R6 structure; the
    // ONLY change vs R6 is the reduce: LDS scatter/gather, ONE round-trip.)
    __shared__ float xps[2][CHUNK * UU];       // scaled x-projection (+K) per chunk
    __shared__ float hist[2][CHUNK * HISTP];   // u history per chunk
    __shared__ __align__(16) float xs[CHUNK * 12];
    __shared__ __align__(8)  f32x2 wdl2[UU];   // -2*Wd rows
    __shared__ __align__(16) float pg[4 * UU]; // partial gather: [unit][quarter]

    const int tid = threadIdx.x;
    const int wid = tid >> 6;    // 0 = scan wave, 1 = producer wave
    const int l   = tid & 63;
    const int b   = blockIdx.x;
    const int g   = l >> 4;
    const int r   = l & 15;

    // --- probe DPP row_ror direction (init-only, direction-proof) ---
    int dstep;
    {
        int q = __builtin_amdgcn_mov_dpp(r, 0x121, 0xF, 0xF, false);
        dstep = (q - r) & 15;
    }

    // --- Wh fragments, scaled: W2'[k,c] = -2*C*Wh[k,c].
    //     Slot j of lane (g,r): unit (r + 16j) over k-quarter g.
    f32x2 w2[4][8];
#pragma unroll
    for (int j = 0; j < 4; ++j) {
        const int cj = r + 16 * j;
#pragma unroll
        for (int m = 0; m < 8; ++m) {
            const int k0 = 16 * g + ((r + (2 * m) * dstep) & 15);
            const int k1 = 16 * g + ((r + (2 * m + 1) * dstep) & 15);
            f32x2 w;
            w.x = -2.0f * CSCALE * Wh[(size_t)k0 * UU + cj];
            w.y = -2.0f * CSCALE * Wh[(size_t)k1 * UU + cj];
            w2[j][m] = w;
        }
    }

    // --- producer-wave constants ---
    f32x2 wxp[5];
#pragma unroll
    for (int d2 = 0; d2 < 5; ++d2) {
        f32x2 w;
        w.x = CSCALE * Wx[(2 * d2) * UU + l];
        w.y = CSCALE * Wx[(2 * d2 + 1) * UU + l];
        wxp[d2] = w;
    }
    float Kl;
    {
        float s = bias[l];
        for (int k = 0; k < UU; ++k) s += Wh[(size_t)k * UU + l];
        Kl = CSCALE * s;
    }
    f32x2 bdd;
    {
        float s0 = bd[0], s1 = bd[1];
        for (int k = 0; k < UU; ++k) { s0 += Wd[k * DOUT + 0]; s1 += Wd[k * DOUT + 1]; }
        bdd.x = s0; bdd.y = s1;
    }
    if (wid == 0) {
        f32x2 w; w.x = -2.0f * Wd[l * DOUT + 0]; w.y = -2.0f * Wd[l * DOUT + 1];
        wdl2[l] = w;
    }

    const float* xb = x + (size_t)b * TT * DIN;
    float*       ob = out + (size_t)b * TT * DOUT;

    // --- producer helpers ---
    auto fill_xps = [&](int cn) {
        const f32x2* xr = (const f32x2*)(xb + (size_t)(cn * CHUNK + l) * DIN);
        f32x2 v0 = xr[0], v1 = xr[1], v2 = xr[2], v3 = xr[3], v4 = xr[4];
        f32x2* dst = (f32x2*)&xs[l * 12];
        dst[0] = v0; dst[1] = v1; dst[2] = v2; dst[3] = v3; dst[4] = v4;
        float* xp_out = &xps[cn & 1][l];
#pragma unroll 4
        for (int s = 0; s < CHUNK; ++s) {
            const float* p = &xs[s * 12];
            f32x4 xa = ((const f32x4*)p)[0];
            f32x4 xc = ((const f32x4*)p)[1];
            f32x2 xe = ((const f32x2*)p)[4];
            f32x2 acc = {Kl, 0.0f};
            acc = pkfma(__builtin_shufflevector(xa, xa, 0, 1), wxp[0], acc);
            acc = pkfma(__builtin_shufflevector(xa, xa, 2, 3), wxp[1], acc);
            acc = pkfma(__builtin_shufflevector(xc, xc, 0, 1), wxp[2], acc);
            acc = pkfma(__builtin_shufflevector(xc, xc, 2, 3), wxp[3], acc);
            acc = pkfma(xe, wxp[4], acc);
            xp_out[s * UU] = acc.x + acc.y;
        }
    };
    auto dense_chunk = [&](int cd) {
        const float* hrow = &hist[cd & 1][l * HISTP];
        f32x2 acc = bdd;
#pragma unroll 8
        for (int k = 0; k < UU; ++k) {
            float u = hrow[k];
            f32x2 uu; uu.x = u; uu.y = u;
            acc = pkfma(uu, wdl2[k], acc);
        }
        float2 o; o.x = acc.x; o.y = acc.y;
        *(float2*)(ob + (size_t)(cd * CHUNK + l) * DOUT) = o;
    };

    // prologue: producer fills chunk 0's x-projection
    if (wid == 1) fill_xps(0);
    __syncthreads();

    // --- scan: R6 body; reduce = LDS scatter/gather (same-wave DS ordering,
    //     ONE round-trip on the chain instead of two exchange hops) ---
    const int wbase = 4 * r + g;   // = 4*unit + quarter for slot j at +64j
    auto scan_chunk = [&](int c, float u) {
        const float* xpsrc = &xps[c & 1][l];
        float* hdst = &hist[c & 1][l];
#pragma unroll 8
        for (int s = 0; s < CHUNK; ++s) {
            float xpv = xpsrc[s * UU];          // independent of u -> hoistable
            // broadcast u within each 16-lane row, direct to pk pairs
            f32x2 hp[8];
            hp[0].x = u;
            ror_fill<1>(__float_as_int(u), hp);
            // dot with -2C*Wh (4 slots: unit r+16j over quarter g)
            f32x2 a0 = {0.f,0.f}, a1 = {0.f,0.f}, a2 = {0.f,0.f}, a3 = {0.f,0.f};
#pragma unroll
            for (int m = 0; m < 8; ++m) {
                a0 = pkfma(hp[m], w2[0][m], a0);
                a1 = pkfma(hp[m], w2[1][m], a1);
                a2 = pkfma(hp[m], w2[2][m], a2);
                a3 = pkfma(hp[m], w2[3][m], a3);
            }
            // scatter partials: pg[4*(r+16j) + g] = slot j
            pg[wbase +   0] = a0.x + a0.y;
            pg[wbase +  64] = a1.x + a1.y;
            pg[wbase + 128] = a2.x + a2.y;
            pg[wbase + 192] = a3.x + a3.y;
            // gather own unit's 4 quarter-partials (in-order DS: sees the
            // writes above from all lanes of this wave, no barrier needed)
            f32x4 zq = *(const f32x4*)&pg[4 * l];
            float zr = (zq.x + zq.y) + (zq.z + zq.w);
            float zp = zr + xpv;                // = C*z
#if __has_builtin(__builtin_amdgcn_exp2f)
            float e = __builtin_amdgcn_exp2f(zp);
#else
            float e = exp2f(zp);
#endif
            u = __builtin_amdgcn_rcpf(e + 1.0f);  // u = 1/(e^{2z}+1); h = 1-2u
            hdst[s * HISTP] = u;
        }
        return u;
    };

    float u = 0.5f;  // h_0 = 0
    for (int c = 0; c < NCHUNK; ++c) {
        if (wid == 0) {
            u = scan_chunk(c, u);
        } else {
            if (c + 1 < NCHUNK) fill_xps(c + 1);
            if (c > 0)          dense_chunk(c - 1);
        }
        __syncthreads();
    }
    if (wid == 1) dense_chunk(NCHUNK - 1);
}

extern "C" void kernel_launch(void* const* d_in, const int* in_sizes, int n_in,
                              void* d_out, int out_size, void* d_ws, size_t ws_size,
                              hipStream_t stream) {
    const float* x    = (const float*)d_in[0];
    const float* Wx   = (const float*)d_in[1];
    const float* Wh   = (const float*)d_in[2];
    const float* bias = (const float*)d_in[3];
    const float* Wd   = (const float*)d_in[4];
    const float* bd   = (const float*)d_in[5];
    float* out = (float*)d_out;

    rnn_scan_kernel<<<BB, 128, 0, stream>>>(x, Wx, Wh, bias, Wd, bd, out);
}

// Round 13
// 324.032 us; speedup vs baseline: 1.2888x; 1.0704x over previous
//
#include <hip/hip_runtime.h>

#define BB     256
#define TT     2048
#define DIN    10
#define UU     64
#define DOUT   2
#define CHUNK  64
#define NCHUNK (TT / CHUNK)
#define HISTP  68   // even mult of 4 -> 16B-aligned b128 quarter reads

typedef float f32x2 __attribute__((ext_vector_type(2)));
typedef float f32x4 __attribute__((ext_vector_type(4)));

// 2*log2(e): recurrence tracked as u = 1/(exp2(C*z)+1), h = 1-2u = tanh(z)
#define CSCALE 2.8853900817779268f

#if __has_builtin(__builtin_elementwise_fma)
__device__ __forceinline__ f32x2 pkfma(f32x2 a, f32x2 b, f32x2 c) {
    return __builtin_elementwise_fma(a, b, c);
}
#else
__device__ __forceinline__ f32x2 pkfma(f32x2 a, f32x2 b, f32x2 c) {
    f32x2 r; r.x = fmaf(a.x, b.x, c.x); r.y = fmaf(a.y, b.y, c.y); return r;
}
#endif

// Quad-local allreduce (sum over the 4 lanes of each quad) — pure VALU DPP.
// quad_perm[1,0,3,2] = 0xB1 and [2,3,0,1] = 0x4E are SELF-INVERSE: identical
// under either "read" or "write" permutation convention (direction-proof).
__device__ __forceinline__ float quadsum(float p) {
    float t = __int_as_float(__builtin_amdgcn_mov_dpp(__float_as_int(p), 0xB1, 0xF, 0xF, false));
    p += t;
    float t2 = __int_as_float(__builtin_amdgcn_mov_dpp(__float_as_int(p), 0x4E, 0xF, 0xF, false));
    return p + t2;
}

__global__ __launch_bounds__(128) void rnn_scan_kernel(
    const float* __restrict__ x,    // [B,T,DIN]
    const float* __restrict__ Wx,   // [DIN,U]
    const float* __restrict__ Wh,   // [U,U]
    const float* __restrict__ bias, // [U]
    const float* __restrict__ Wd,   // [U,DOUT]
    const float* __restrict__ bd,   // [DOUT]
    float* __restrict__ out)        // [B,T,DOUT]
{
    // Wave 0 (consumer): recurrence; state handoff via the hist row itself
    // (one ds_write -> 4 broadcast ds_read_b128 round-trip per step; the
    // cross-quarter reduce is quad-local DPP, no DS hops).
    // Wave 1 (producer): x-projection for chunk c+1, Dense for chunk c-1.
    __shared__ float xps[2][CHUNK * UU];            // scaled x-projection (+K)
    __shared__ __align__(16) float hist[2][CHUNK * HISTP]; // u history = h state
    __shared__ __align__(16) float xs[CHUNK * 12];
    __shared__ __align__(8)  f32x2 wdl2[UU];        // -2*Wd rows

    const int tid = threadIdx.x;
    const int wid = tid >> 6;    // 0 = scan wave, 1 = producer wave
    const int l   = tid & 63;
    const int b   = blockIdx.x;
    const int qb  = l & 3;       // k-quarter this lane covers: k in [16qb, 16qb+16)
    const int ub  = l & ~3;      // unit base: slot j -> unit ub|j ; own unit = l

    // --- Wh fragments, scaled: W2'[k,c] = -2*C*Wh[k,c].
    //     Slot j of lane l: unit (ub|j) over k-quarter qb. No lane permutation.
    f32x2 w2[4][8];
#pragma unroll
    for (int j = 0; j < 4; ++j) {
        const int cj = ub | j;
#pragma unroll
        for (int m = 0; m < 8; ++m) {
            const int k0 = 16 * qb + 2 * m;
            f32x2 w;
            w.x = -2.0f * CSCALE * Wh[(size_t)k0 * UU + cj];
            w.y = -2.0f * CSCALE * Wh[(size_t)(k0 + 1) * UU + cj];
            w2[j][m] = w;
        }
    }

    // --- producer-wave constants ---
    f32x2 wxp[5];
#pragma unroll
    for (int d2 = 0; d2 < 5; ++d2) {
        f32x2 w;
        w.x = CSCALE * Wx[(2 * d2) * UU + l];
        w.y = CSCALE * Wx[(2 * d2 + 1) * UU + l];
        wxp[d2] = w;
    }
    float Kl;
    {
        float s = bias[l];
        for (int k = 0; k < UU; ++k) s += Wh[(size_t)k * UU + l];
        Kl = CSCALE * s;
    }
    f32x2 bdd;
    {
        float s0 = bd[0], s1 = bd[1];
        for (int k = 0; k < UU; ++k) { s0 += Wd[k * DOUT + 0]; s1 += Wd[k * DOUT + 1]; }
        bdd.x = s0; bdd.y = s1;
    }

    float* prev = &hist[1][63 * HISTP];   // scan state pointer (prev u row)
    if (wid == 0) {
        f32x2 w; w.x = -2.0f * Wd[l * DOUT + 0]; w.y = -2.0f * Wd[l * DOUT + 1];
        wdl2[l] = w;
        prev[l] = 0.5f;                   // h_0 = 0  (u = 0.5)
    }

    const float* xb = x + (size_t)b * TT * DIN;
    float*       ob = out + (size_t)b * TT * DOUT;

    // --- producer helpers (unchanged from R6) ---
    auto fill_xps = [&](int cn) {
        const f32x2* xr = (const f32x2*)(xb + (size_t)(cn * CHUNK + l) * DIN);
        f32x2 v0 = xr[0], v1 = xr[1], v2 = xr[2], v3 = xr[3], v4 = xr[4];
        f32x2* dst = (f32x2*)&xs[l * 12];
        dst[0] = v0; dst[1] = v1; dst[2] = v2; dst[3] = v3; dst[4] = v4;
        float* xp_out = &xps[cn & 1][l];
#pragma unroll 4
        for (int s = 0; s < CHUNK; ++s) {
            const float* p = &xs[s * 12];
            f32x4 xa = ((const f32x4*)p)[0];
            f32x4 xc = ((const f32x4*)p)[1];
            f32x2 xe = ((const f32x2*)p)[4];
            f32x2 acc = {Kl, 0.0f};
            acc = pkfma(__builtin_shufflevector(xa, xa, 0, 1), wxp[0], acc);
            acc = pkfma(__builtin_shufflevector(xa, xa, 2, 3), wxp[1], acc);
            acc = pkfma(__builtin_shufflevector(xc, xc, 0, 1), wxp[2], acc);
            acc = pkfma(__builtin_shufflevector(xc, xc, 2, 3), wxp[3], acc);
            acc = pkfma(xe, wxp[4], acc);
            xp_out[s * UU] = acc.x + acc.y;
        }
    };
    auto dense_chunk = [&](int cd) {
        const float* hrow = &hist[cd & 1][l * HISTP];
        f32x2 acc = bdd;
#pragma unroll 8
        for (int k = 0; k < UU; ++k) {
            float u = hrow[k];
            f32x2 uu; uu.x = u; uu.y = u;
            acc = pkfma(uu, wdl2[k], acc);
        }
        float2 o; o.x = acc.x; o.y = acc.y;
        *(float2*)(ob + (size_t)(cd * CHUNK + l) * DOUT) = o;
    };

    // prologue: producer fills chunk 0's x-projection
    if (wid == 1) fill_xps(0);
    __syncthreads();

    // --- scan: one DS round-trip per step; reduce = quad-local DPP ---
    auto scan_chunk = [&](int c) {
        const float* xpsrc = &xps[c & 1][l];
        float* hbuf = &hist[c & 1][0];
#pragma unroll 8
        for (int s = 0; s < CHUNK; ++s) {
            float xpv = xpsrc[s * UU];          // independent -> hoistable
            // broadcast read: this lane's k-quarter of prev u row.
            // Only 4 distinct addresses wave-wide -> LDS broadcast.
            const f32x4* hq = (const f32x4*)(prev + 16 * qb);
            f32x4 q0 = hq[0], q1 = hq[1], q2 = hq[2], q3 = hq[3];
            f32x2 hp[8];
            hp[0].x = q0.x; hp[0].y = q0.y;  hp[1].x = q0.z; hp[1].y = q0.w;
            hp[2].x = q1.x; hp[2].y = q1.y;  hp[3].x = q1.z; hp[3].y = q1.w;
            hp[4].x = q2.x; hp[4].y = q2.y;  hp[5].x = q2.z; hp[5].y = q2.w;
            hp[6].x = q3.x; hp[6].y = q3.y;  hp[7].x = q3.z; hp[7].y = q3.w;
            // dot with -2C*Wh (slot j = unit ub|j over quarter qb)
            f32x2 a0 = {0.f,0.f}, a1 = {0.f,0.f}, a2 = {0.f,0.f}, a3 = {0.f,0.f};
#pragma unroll
            for (int m = 0; m < 8; ++m) {
                a0 = pkfma(hp[m], w2[0][m], a0);
                a1 = pkfma(hp[m], w2[1][m], a1);
                a2 = pkfma(hp[m], w2[2][m], a2);
                a3 = pkfma(hp[m], w2[3][m], a3);
            }
            // quad-local allreduce: sum the 4 quarters (lanes of the quad)
            float p0 = quadsum(a0.x + a0.y);
            float p1 = quadsum(a1.x + a1.y);
            float p2 = quadsum(a2.x + a2.y);
            float p3 = quadsum(a3.x + a3.y);
            // own unit = l  (slot j == qb)
            float zlo = (qb & 1) ? p1 : p0;
            float zhi = (qb & 1) ? p3 : p2;
            float zr  = (qb & 2) ? zhi : zlo;
            float zp = zr + xpv;                // = C*z
#if __has_builtin(__builtin_amdgcn_exp2f)
            float e = __builtin_amdgcn_exp2f(zp);
#else
            float e = exp2f(zp);
#endif
            float u = __builtin_amdgcn_rcpf(e + 1.0f);  // h = 1-2u
            float* hrow = hbuf + s * HISTP;
            hrow[l] = u;                        // state handoff AND hist
            prev = hrow;
        }
    };

    for (int c = 0; c < NCHUNK; ++c) {
        if (wid == 0) {
            scan_chunk(c);
        } else {
            if (c + 1 < NCHUNK) fill_xps(c + 1);
            if (c > 0)          dense_chunk(c - 1);
        }
        __syncthreads();
    }
    if (wid == 1) dense_chunk(NCHUNK - 1);
}

extern "C" void kernel_launch(void* const* d_in, const int* in_sizes, int n_in,
                              void* d_out, int out_size, void* d_ws, size_t ws_size,
                              hipStream_t stream) {
    const float* x    = (const float*)d_in[0];
    const float* Wx   = (const float*)d_in[1];
    const float* Wh   = (const float*)d_in[2];
    const float* bias = (const float*)d_in[3];
    const float* Wd   = (const float*)d_in[4];
    const float* bd   = (const float*)d_in[5];
    float* out = (float*)d_out;

    rnn_scan_kernel<<<BB, 128, 0, stream>>>(x, Wx, Wh, bias, Wd, bd, out);
}